// Round 4
// baseline (134.805 us; speedup 1.0000x reference)
//
#include <hip/hip_runtime.h>
#include <math.h>

#define EPSN 1e-4f
#define SEQ 2304

using bf16x8 = __attribute__((ext_vector_type(8))) short;
using f32x4  = __attribute__((ext_vector_type(4))) float;

__device__ inline unsigned short f2bf(float x) {
    union { float f; unsigned u; } c; c.f = x;
    unsigned u = c.u;
    u += 0x7fffu + ((u >> 16) & 1u);
    return (unsigned short)(u >> 16);
}

// HW packed f32->bf16 (RNE), gfx950.
__device__ inline unsigned cvt_pk_bf16(float lo, float hi) {
    unsigned r;
    asm("v_cvt_pk_bf16_f32 %0, %1, %2" : "=v"(r) : "v"(lo), "v"(hi));
    return r;
}
// gfx950 cross-row swaps (verified passing in R3).
__device__ inline void permlane32_swap(unsigned &a, unsigned &b) {
    asm("v_permlane32_swap_b32 %0, %1" : "+v"(a), "+v"(b));
}
__device__ inline void permlane16_swap(unsigned &a, unsigned &b) {
    asm("v_permlane16_swap_b32 %0, %1" : "+v"(a), "+v"(b));
}

// ---------------- Kernel 1: prep = weight-norm (blocks 0..255) + x-transpose ----------------
__global__ __launch_bounds__(256) void prep_kernel(const float* __restrict__ w_qkv,
                                                   const float* __restrict__ w_out,
                                                   const float* __restrict__ x,
                                                   unsigned short* __restrict__ wqb,
                                                   unsigned short* __restrict__ wob,
                                                   unsigned short* __restrict__ xt) {
    __shared__ __align__(16) unsigned short T[64][80];
    int bid = blockIdx.x;
    if (bid < 256) {
        int wave = threadIdx.x >> 6, lane = threadIdx.x & 63;
        int row = bid * 4 + wave;
        const float* src;
        unsigned short* dst;
        if (row < 768) { src = w_qkv + (size_t)row * 256; dst = wqb + (size_t)row * 256; }
        else           { src = w_out + (size_t)(row - 768) * 256; dst = wob + (size_t)(row - 768) * 256; }
        float4 v = *(const float4*)&src[lane * 4];
        float ss = v.x * v.x + v.y * v.y + v.z * v.z + v.w * v.w;
        for (int off = 32; off > 0; off >>= 1) ss += __shfl_xor(ss, off, 64);
        float sc = 1.0f / (sqrtf(ss) + 16.0f * EPSN);
        unsigned p0 = (unsigned)f2bf(v.x * sc) | ((unsigned)f2bf(v.y * sc) << 16);
        unsigned p1 = (unsigned)f2bf(v.z * sc) | ((unsigned)f2bf(v.w * sc) << 16);
        *(uint2*)&dst[lane * 4] = make_uint2(p0, p1);
    } else {
        int e0 = bid - 256;            // 0..287
        int st = e0 % 36, ct = (e0 / 36) & 3, n = e0 / 144;
        int t = threadIdx.x;
#pragma unroll
        for (int p = 0; p < 4; ++p) {
            int e = t + p * 256;
            int c = e >> 4, sv = (e & 15) * 4;
            float4 v = *(const float4*)&x[(size_t)(n * 256 + ct * 64 + c) * SEQ + st * 64 + sv];
            T[sv + 0][c] = f2bf(v.x);
            T[sv + 1][c] = f2bf(v.y);
            T[sv + 2][c] = f2bf(v.z);
            T[sv + 3][c] = f2bf(v.w);
        }
        __syncthreads();
#pragma unroll
        for (int p = 0; p < 2; ++p) {
            int e = t + p * 256;
            int s = e >> 3, cb = (e & 7) * 8;
            uint4 v = *(const uint4*)&T[s][cb];
            *(uint4*)&xt[(size_t)(n * SEQ + st * 64 + s) * 256 + ct * 64 + cb] = v;
        }
    }
}

// ---------------- Kernel 2: fused QKV GEMM + d-normalize ----------------
// Flat grid 576 with XCD-bijective swizzle: each XCD owns 9 (st,n) tiles for ALL 8
// heads -> the shared xt tile is fetched into exactly one L2.
__global__ __launch_bounds__(256) void qkv_fused_kernel(const unsigned short* __restrict__ xt,
                                                        const unsigned short* __restrict__ wqb,
                                                        unsigned short* __restrict__ qn,
                                                        unsigned short* __restrict__ kn,
                                                        unsigned short* __restrict__ vn) {
    __shared__ float Cs[96][65];
    __shared__ __align__(16) unsigned short Vls[32][72];
    int bid = blockIdx.x;
    int xcd = bid & 7, j = bid >> 3;        // j 0..71
    int h = j & 7;
    int tilej = xcd * 9 + (j >> 3);         // 0..71
    int st = tilej % 36, n = tilej / 36;
    int tid = threadIdx.x;
    int wave = tid >> 6, lane = tid & 63;
    int ln = lane & 15, quad = lane >> 4;
    const unsigned short* Abase = wqb + (size_t)(h * 96 + ln) * 256 + quad * 8;
    const unsigned short* Bbase = xt + (size_t)(n * SEQ + st * 64 + wave * 16 + ln) * 256 + quad * 8;
    f32x4 acc[6];
#pragma unroll
    for (int m = 0; m < 6; ++m) acc[m] = (f32x4){0.f, 0.f, 0.f, 0.f};
#pragma unroll
    for (int kc = 0; kc < 8; ++kc) {
        bf16x8 b = *(const bf16x8*)(Bbase + kc * 32);
#pragma unroll
        for (int m = 0; m < 6; ++m) {
            bf16x8 a = *(const bf16x8*)(Abase + (size_t)(m * 16) * 256 + kc * 32);
            acc[m] = __builtin_amdgcn_mfma_f32_16x16x32_bf16(a, b, acc[m], 0, 0, 0);
        }
    }
#pragma unroll
    for (int m = 0; m < 6; ++m)
#pragma unroll
        for (int r = 0; r < 4; ++r)
            Cs[m * 16 + quad * 4 + r][wave * 16 + ln] = acc[m][r];
    __syncthreads();
    int nh = n * 8 + h;
    if (tid < 192) {
        int sl = tid & 63, wh = tid >> 6;
        int s = st * 64 + sl;
        float v[32];
        float ss = 0.f;
#pragma unroll
        for (int d = 0; d < 32; ++d) { v[d] = Cs[3 * d + wh][sl]; ss += v[d] * v[d]; }
        float inv = 1.0f / (EPSN + sqrtf(ss * (1.0f / 32.0f)));
        // fold softmax scale (1/sqrt(32)) AND log2(e) into q so attn uses exp2
        if (wh == 0) inv *= 0.17677669529663687f * 1.4426950408889634f;
        if (wh == 2) {
#pragma unroll
            for (int d = 0; d < 32; ++d) Vls[d][sl] = f2bf(v[d] * inv);
        } else {
            unsigned short* dst = (wh == 1 ? kn : qn) + (size_t)nh * 73728 + (size_t)s * 32;
            unsigned wbuf[16];
#pragma unroll
            for (int j2 = 0; j2 < 16; ++j2)
                wbuf[j2] = (unsigned)f2bf(v[2 * j2] * inv) | ((unsigned)f2bf(v[2 * j2 + 1] * inv) << 16);
#pragma unroll
            for (int j2 = 0; j2 < 4; ++j2) {
                uint4 t4 = make_uint4(wbuf[4 * j2], wbuf[4 * j2 + 1], wbuf[4 * j2 + 2], wbuf[4 * j2 + 3]);
                *(uint4*)(dst + j2 * 8) = t4;
            }
        }
    }
    __syncthreads();
    {
        int d = tid >> 3, sj = (tid & 7) * 8;
        uint4 t4 = *(const uint4*)&Vls[d][sj];
        *(uint4*)&vn[(size_t)nh * 73728 + (size_t)d * SEQ + st * 64 + sj] = t4;
    }
}

// ---------------- Kernel 3: MFMA flash attention, in-block split-K=2, 2-deep staging ----------------
// 512 threads = 2 k-groups x 4 q-subtiles. Loads for tile i+2 are issued at the top of
// iter i (hand-unrolled even/odd so staging regs are statically indexed) -> latency
// window ~1.5 iterations. l accumulated as scalar f32 (no `ones` MFMA), reduced with
// 2 shfl_xor at the end.
__global__ __launch_bounds__(512) void attn_mfma_kernel(const unsigned short* __restrict__ qn,
                                                        const unsigned short* __restrict__ kn,
                                                        const unsigned short* __restrict__ vn,
                                                        unsigned short* __restrict__ y2t) {
    __shared__ __align__(16) unsigned char SM[38912];
    unsigned short (*Ks)[64][40] = (unsigned short (*)[64][40])SM;            // [4] = [kg*2+buf]
    unsigned short (*Vs)[32][72] = (unsigned short (*)[32][72])(SM + 20480);  // [4]
    int tid = threadIdx.x;
    int wave = tid >> 6, lane = tid & 63;
    int ln = lane & 15, quad = lane >> 4;
    int kg = wave >> 2, wq = wave & 3;
    // XCD-aware swizzle: each XCD sees only 2 heads' K/V
    int bid = blockIdx.x;
    int xcd = bid & 7, bi = bid >> 3;
    int nh = xcd * 2 + (bi >= 36);
    int qt = (bi >= 36) ? bi - 36 : bi;
    int n = nh >> 3, h = nh & 7;
    const unsigned short* Qg = qn + (size_t)nh * 73728;
    const unsigned short* Kg = kn + (size_t)nh * 73728;
    const unsigned short* Vg = vn + (size_t)nh * 73728;

    bf16x8 qf = *(const bf16x8*)(Qg + (size_t)(qt * 64 + wq * 16 + ln) * 32 + quad * 8);

    f32x4 o0 = {0.f, 0.f, 0.f, 0.f};
    f32x4 o1 = {0.f, 0.f, 0.f, 0.f};
    float lsum = 0.f;

    int ts = tid & 255;          // staging index within k-group
    int kg2 = kg * 2;
    int s0 = kg * 18 * 64;       // group's first s

    auto compute_tile = [&](int bsel) {
        const f32x4 zero = {0.f, 0.f, 0.f, 0.f};
        unsigned w[4][2];
#pragma unroll
        for (int c = 0; c < 4; ++c) {
            bf16x8 kf = *(const bf16x8*)(&Ks[bsel][c * 16 + ln][quad * 8]);
            // swapped: lane holds S[q=ln][k=c*16+quad*4+r]
            f32x4 sc = __builtin_amdgcn_mfma_f32_16x16x32_bf16(kf, qf, zero, 0, 0, 0);
            float e0 = exp2f(sc[0]), e1 = exp2f(sc[1]);
            float e2 = exp2f(sc[2]), e3 = exp2f(sc[3]);
            lsum += (e0 + e1) + (e2 + e3);
            w[c][0] = cvt_pk_bf16(e0, e1);
            w[c][1] = cvt_pk_bf16(e2, e3);
        }
#pragma unroll
        for (int kc = 0; kc < 2; ++kc) {
            unsigned a0 = w[2 * kc][0], b0 = w[2 * kc + 1][0];
            permlane32_swap(a0, b0);
            permlane16_swap(a0, b0);
            unsigned a1 = w[2 * kc][1], b1 = w[2 * kc + 1][1];
            permlane32_swap(a1, b1);
            permlane16_swap(a1, b1);
            union { unsigned u[4]; bf16x8 v8; } pk;
            pk.u[0] = a0; pk.u[1] = a1; pk.u[2] = b0; pk.u[3] = b1;
            bf16x8 v0 = *(const bf16x8*)(&Vs[bsel][ln][kc * 32 + quad * 8]);
            bf16x8 v1 = *(const bf16x8*)(&Vs[bsel][16 + ln][kc * 32 + quad * 8]);
            o0 = __builtin_amdgcn_mfma_f32_16x16x32_bf16(pk.v8, v0, o0, 0, 0, 0);
            o1 = __builtin_amdgcn_mfma_f32_16x16x32_bf16(pk.v8, v1, o1, 0, 0, 0);
        }
    };

    // prologue: tile 0 -> LDS buf0; tile 1 -> regs B
    uint4 kA = *(const uint4*)(Kg + (size_t)s0 * 32 + ts * 8);
    uint4 vA = *(const uint4*)(Vg + (size_t)(ts >> 3) * SEQ + s0 + (ts & 7) * 8);
    *(uint4*)(&Ks[kg2][ts >> 2][(ts & 3) * 8]) = kA;
    *(uint4*)(&Vs[kg2][ts >> 3][(ts & 7) * 8]) = vA;
    uint4 kB = *(const uint4*)(Kg + (size_t)(s0 + 64) * 32 + ts * 8);
    uint4 vB = *(const uint4*)(Vg + (size_t)(ts >> 3) * SEQ + (s0 + 64) + (ts & 7) * 8);

    for (int i = 0; i < 18; i += 2) {
        // even iter: prefetch tile i+2 -> A; compute buf0 (tile i); write buf1 <- B (tile i+1)
        if (i + 2 < 18) {
            int sn = s0 + (i + 2) * 64;
            kA = *(const uint4*)(Kg + (size_t)sn * 32 + ts * 8);
            vA = *(const uint4*)(Vg + (size_t)(ts >> 3) * SEQ + sn + (ts & 7) * 8);
        }
        __syncthreads();
        compute_tile(kg2);
        *(uint4*)(&Ks[kg2 + 1][ts >> 2][(ts & 3) * 8]) = kB;
        *(uint4*)(&Vs[kg2 + 1][ts >> 3][(ts & 7) * 8]) = vB;
        // odd iter: prefetch tile i+3 -> B; compute buf1 (tile i+1); write buf0 <- A (tile i+2)
        if (i + 3 < 18) {
            int sn = s0 + (i + 3) * 64;
            kB = *(const uint4*)(Kg + (size_t)sn * 32 + ts * 8);
            vB = *(const uint4*)(Vg + (size_t)(ts >> 3) * SEQ + sn + (ts & 7) * 8);
        }
        __syncthreads();
        compute_tile(kg2 + 1);
        if (i + 2 < 18) {
            *(uint4*)(&Ks[kg2][ts >> 2][(ts & 3) * 8]) = kA;
            *(uint4*)(&Vs[kg2][ts >> 3][(ts & 7) * 8]) = vA;
        }
    }

    // reduce l across the 4 quad-rows (each lane then holds l for q=ln of its k-group)
    lsum += __shfl_xor(lsum, 16, 64);
    lsum += __shfl_xor(lsum, 32, 64);

    // ---- epilogue: combine the two k-groups, normalize, store ----
    __syncthreads();                               // all K/V reads done; safe to alias LDS
    float (*Os)[36] = (float (*)[36])SM;           // [128][36] f32
    float* Ls = (float*)(SM + 128 * 36 * 4);       // [128]
#pragma unroll
    for (int r = 0; r < 4; ++r) {
        int q = wq * 16 + quad * 4 + r;
        Os[kg * 64 + q][ln] = o0[r];
        Os[kg * 64 + q][16 + ln] = o1[r];
    }
    if (quad == 0) Ls[kg * 64 + wq * 16 + ln] = lsum;
    __syncthreads();
    {
        int q = tid >> 3, dg = (tid & 7) * 4;
        float inv = 1.0f / (Ls[q] + Ls[64 + q]);
        float r0 = (Os[q][dg + 0] + Os[64 + q][dg + 0]) * inv;
        float r1 = (Os[q][dg + 1] + Os[64 + q][dg + 1]) * inv;
        float r2 = (Os[q][dg + 2] + Os[64 + q][dg + 2]) * inv;
        float r3 = (Os[q][dg + 3] + Os[64 + q][dg + 3]) * inv;
        *(uint2*)&y2t[((size_t)(n * SEQ) + qt * 64 + q) * 256 + h * 32 + dg] =
            make_uint2(cvt_pk_bf16(r0, r1), cvt_pk_bf16(r2, r3));
    }
}

// ---------------- Kernel 4: out GEMM (bf16 MFMA, LDS-free) + residual ----------------
// grid (72,4,2): blocks sharing the y2t B-tile (mt=0..3, linear stride 72, 72%8==0)
// land on the SAME XCD -> B-tile served from one L2.
__global__ __launch_bounds__(256) void out_gemm_kernel(const unsigned short* __restrict__ y2t,
                                                       const unsigned short* __restrict__ wob,
                                                       const float* __restrict__ x,
                                                       float* __restrict__ out) {
    int st = blockIdx.x;   // 0..71
    int mt = blockIdx.y;   // 0..3
    int n  = blockIdx.z;
    int tid = threadIdx.x;
    int wave = tid >> 6, lane = tid & 63;
    int ln = lane & 15, quad = lane >> 4;
    int m0 = mt * 64 + wave * 16;
    const unsigned short* Abase = wob + (size_t)(m0 + ln) * 256 + quad * 8;
    const unsigned short* Bbase = y2t + (size_t)(n * SEQ + st * 32 + ln) * 256 + quad * 8;
    f32x4 acc[2];
#pragma unroll
    for (int c = 0; c < 2; ++c) acc[c] = (f32x4){0.f, 0.f, 0.f, 0.f};
#pragma unroll
    for (int kc = 0; kc < 8; ++kc) {
        bf16x8 a = *(const bf16x8*)(Abase + kc * 32);
#pragma unroll
        for (int c = 0; c < 2; ++c) {
            bf16x8 b = *(const bf16x8*)(Bbase + (size_t)(c * 16) * 256 + kc * 32);
            acc[c] = __builtin_amdgcn_mfma_f32_16x16x32_bf16(a, b, acc[c], 0, 0, 0);
        }
    }
    const float c0f = 0.7f * 1.3130643285972254f;
    const float c1f = 0.3f * 1.3130643285972254f;
#pragma unroll
    for (int c = 0; c < 2; ++c)
#pragma unroll
        for (int r = 0; r < 4; ++r) {
            int o = m0 + quad * 4 + r;
            int s = st * 32 + c * 16 + ln;
            size_t idx = (size_t)(n * 256 + o) * SEQ + s;
            out[idx] = c0f * x[idx] + c1f * acc[c][r];
        }
}

extern "C" void kernel_launch(void* const* d_in, const int* in_sizes, int n_in,
                              void* d_out, int out_size, void* d_ws, size_t ws_size,
                              hipStream_t stream) {
    (void)in_sizes; (void)n_in; (void)out_size; (void)ws_size;
    const float* x     = (const float*)d_in[0];
    const float* w_qkv = (const float*)d_in[1];
    const float* w_out = (const float*)d_in[2];
    float* out = (float*)d_out;
    float* ws  = (float*)d_ws;
    unsigned short* wqb = (unsigned short*)(ws);             // 98304 f
    unsigned short* wob = (unsigned short*)(ws + 98304);     // 32768 f
    unsigned short* xt  = (unsigned short*)(ws + 131072);    // 589824 f (dead after qkv)
    unsigned short* y2t = (unsigned short*)(ws + 131072);    // alias of xt
    unsigned short* qn  = (unsigned short*)(ws + 720896);
    unsigned short* kn  = (unsigned short*)(ws + 1310720);
    unsigned short* vn  = (unsigned short*)(ws + 1900544);

    hipLaunchKernelGGL(prep_kernel, dim3(544), dim3(256), 0, stream,
                       w_qkv, w_out, x, wqb, wob, xt);
    hipLaunchKernelGGL(qkv_fused_kernel, dim3(576), dim3(256), 0, stream,
                       xt, wqb, qn, kn, vn);
    hipLaunchKernelGGL(attn_mfma_kernel, dim3(576), dim3(512), 0, stream,
                       qn, kn, vn, y2t);
    hipLaunchKernelGGL(out_gemm_kernel, dim3(72, 4, 2), dim3(256), 0, stream,
                       y2t, wob, x, out);
}

// Round 5
// 134.709 us; speedup vs baseline: 1.0007x; 1.0007x over previous
//
#include <hip/hip_runtime.h>
#include <math.h>

#define EPSN 1e-4f
#define SEQ 2304

using bf16x8 = __attribute__((ext_vector_type(8))) short;
using f32x4  = __attribute__((ext_vector_type(4))) float;

__device__ inline unsigned short f2bf(float x) {
    union { float f; unsigned u; } c; c.f = x;
    unsigned u = c.u;
    u += 0x7fffu + ((u >> 16) & 1u);
    return (unsigned short)(u >> 16);
}

// HW packed f32->bf16 (RNE), gfx950.
__device__ inline unsigned cvt_pk_bf16(float lo, float hi) {
    unsigned r;
    asm("v_cvt_pk_bf16_f32 %0, %1, %2" : "=v"(r) : "v"(lo), "v"(hi));
    return r;
}
// gfx950 cross-row swaps (verified passing in R3/R4).
__device__ inline void permlane32_swap(unsigned &a, unsigned &b) {
    asm("v_permlane32_swap_b32 %0, %1" : "+v"(a), "+v"(b));
}
__device__ inline void permlane16_swap(unsigned &a, unsigned &b) {
    asm("v_permlane16_swap_b32 %0, %1" : "+v"(a), "+v"(b));
}

// ---------------- Kernel 1: prep = weight-norm (blocks 0..255) + x-transpose (4x finer) ----------------
__global__ __launch_bounds__(256) void prep_kernel(const float* __restrict__ w_qkv,
                                                   const float* __restrict__ w_out,
                                                   const float* __restrict__ x,
                                                   unsigned short* __restrict__ wqb,
                                                   unsigned short* __restrict__ wob,
                                                   unsigned short* __restrict__ xt) {
    __shared__ __align__(16) unsigned short T[16][72];
    int bid = blockIdx.x;
    if (bid < 256) {
        int wave = threadIdx.x >> 6, lane = threadIdx.x & 63;
        int row = bid * 4 + wave;
        const float* src;
        unsigned short* dst;
        if (row < 768) { src = w_qkv + (size_t)row * 256; dst = wqb + (size_t)row * 256; }
        else           { src = w_out + (size_t)(row - 768) * 256; dst = wob + (size_t)(row - 768) * 256; }
        float4 v = *(const float4*)&src[lane * 4];
        float ss = v.x * v.x + v.y * v.y + v.z * v.z + v.w * v.w;
        for (int off = 32; off > 0; off >>= 1) ss += __shfl_xor(ss, off, 64);
        float sc = 1.0f / (sqrtf(ss) + 16.0f * EPSN);
        unsigned p0 = (unsigned)f2bf(v.x * sc) | ((unsigned)f2bf(v.y * sc) << 16);
        unsigned p1 = (unsigned)f2bf(v.z * sc) | ((unsigned)f2bf(v.w * sc) << 16);
        *(uint2*)&dst[lane * 4] = make_uint2(p0, p1);
    } else {
        // transpose x[n][c][s] -> xt[n][s][c] bf16; unit = 64c x 16s (1152 blocks)
        int e0 = bid - 256;            // 0..1151
        int n = e0 / 576;
        int r = e0 % 576;
        int ct = r / 144;
        int r2 = r % 144;
        int st = r2 >> 2, sq = r2 & 3;
        int tid = threadIdx.x;
        int c = tid >> 2, sv = (tid & 3) * 4;
        float4 v = *(const float4*)&x[(size_t)(n * 256 + ct * 64 + c) * SEQ + st * 64 + sq * 16 + sv];
        T[sv + 0][c] = f2bf(v.x);
        T[sv + 1][c] = f2bf(v.y);
        T[sv + 2][c] = f2bf(v.z);
        T[sv + 3][c] = f2bf(v.w);
        __syncthreads();
        int s = tid >> 4, cb = (tid & 15) * 4;
        uint2 t2 = *(const uint2*)&T[s][cb];
        *(uint2*)&xt[(size_t)(n * SEQ + st * 64 + sq * 16 + s) * 256 + ct * 64 + cb] = t2;
    }
}

// ---------------- Kernel 2: fused QKV GEMM + d-normalize (unchanged from R4) ----------------
__global__ __launch_bounds__(256) void qkv_fused_kernel(const unsigned short* __restrict__ xt,
                                                        const unsigned short* __restrict__ wqb,
                                                        unsigned short* __restrict__ qn,
                                                        unsigned short* __restrict__ kn,
                                                        unsigned short* __restrict__ vn) {
    __shared__ float Cs[96][65];
    __shared__ __align__(16) unsigned short Vls[32][72];
    int bid = blockIdx.x;
    int xcd = bid & 7, j = bid >> 3;        // j 0..71
    int h = j & 7;
    int tilej = xcd * 9 + (j >> 3);         // 0..71
    int st = tilej % 36, n = tilej / 36;
    int tid = threadIdx.x;
    int wave = tid >> 6, lane = tid & 63;
    int ln = lane & 15, quad = lane >> 4;
    const unsigned short* Abase = wqb + (size_t)(h * 96 + ln) * 256 + quad * 8;
    const unsigned short* Bbase = xt + (size_t)(n * SEQ + st * 64 + wave * 16 + ln) * 256 + quad * 8;
    f32x4 acc[6];
#pragma unroll
    for (int m = 0; m < 6; ++m) acc[m] = (f32x4){0.f, 0.f, 0.f, 0.f};
#pragma unroll
    for (int kc = 0; kc < 8; ++kc) {
        bf16x8 b = *(const bf16x8*)(Bbase + kc * 32);
#pragma unroll
        for (int m = 0; m < 6; ++m) {
            bf16x8 a = *(const bf16x8*)(Abase + (size_t)(m * 16) * 256 + kc * 32);
            acc[m] = __builtin_amdgcn_mfma_f32_16x16x32_bf16(a, b, acc[m], 0, 0, 0);
        }
    }
#pragma unroll
    for (int m = 0; m < 6; ++m)
#pragma unroll
        for (int r = 0; r < 4; ++r)
            Cs[m * 16 + quad * 4 + r][wave * 16 + ln] = acc[m][r];
    __syncthreads();
    int nh = n * 8 + h;
    if (tid < 192) {
        int sl = tid & 63, wh = tid >> 6;
        int s = st * 64 + sl;
        float v[32];
        float ss = 0.f;
#pragma unroll
        for (int d = 0; d < 32; ++d) { v[d] = Cs[3 * d + wh][sl]; ss += v[d] * v[d]; }
        float inv = 1.0f / (EPSN + sqrtf(ss * (1.0f / 32.0f)));
        // fold softmax scale (1/sqrt(32)) AND log2(e) into q so attn uses exp2
        if (wh == 0) inv *= 0.17677669529663687f * 1.4426950408889634f;
        if (wh == 2) {
#pragma unroll
            for (int d = 0; d < 32; ++d) Vls[d][sl] = f2bf(v[d] * inv);
        } else {
            unsigned short* dst = (wh == 1 ? kn : qn) + (size_t)nh * 73728 + (size_t)s * 32;
            unsigned wbuf[16];
#pragma unroll
            for (int j2 = 0; j2 < 16; ++j2)
                wbuf[j2] = (unsigned)f2bf(v[2 * j2] * inv) | ((unsigned)f2bf(v[2 * j2 + 1] * inv) << 16);
#pragma unroll
            for (int j2 = 0; j2 < 4; ++j2) {
                uint4 t4 = make_uint4(wbuf[4 * j2], wbuf[4 * j2 + 1], wbuf[4 * j2 + 2], wbuf[4 * j2 + 3]);
                *(uint4*)(dst + j2 * 8) = t4;
            }
        }
    }
    __syncthreads();
    {
        int d = tid >> 3, sj = (tid & 7) * 8;
        uint4 t4 = *(const uint4*)&Vls[d][sj];
        *(uint4*)&vn[(size_t)nh * 73728 + (size_t)d * SEQ + st * 64 + sj] = t4;
    }
}

// ---------------- Kernel 3: MFMA flash attention, split-K=2 ACROSS blocks ----------------
// grid 1152 flat (XCD-swizzled), 256 thr = 4 waves (one q-subtile each), 18 k-tiles,
// 19.5KB LDS, 2-deep register staging, permlane P-redistribute, ones-MFMA row-sum.
__global__ __launch_bounds__(256) void attn_mfma_kernel(const unsigned short* __restrict__ qn,
                                                        const unsigned short* __restrict__ kn,
                                                        const unsigned short* __restrict__ vn,
                                                        float* __restrict__ Opart,
                                                        float* __restrict__ Lpart) {
    __shared__ __align__(16) unsigned short Ks[2][64][40];
    __shared__ __align__(16) unsigned short Vs[2][32][72];
    int tid = threadIdx.x;
    int wq = tid >> 6, lane = tid & 63;
    int ln = lane & 15, quad = lane >> 4;
    // XCD swizzle: 1152 = 8 * 144; each XCD owns 2 heads (both kz, all qt)
    int bid = blockIdx.x;
    int xcd = bid & 7, bi = bid >> 3;       // bi 0..143
    int nh = xcd * 2 + (bi >= 72);
    int bi2 = (bi >= 72) ? bi - 72 : bi;    // 0..71
    int qt = bi2 % 36, kz = bi2 / 36;
    const unsigned short* Qg = qn + (size_t)nh * 73728;
    const unsigned short* Kg = kn + (size_t)nh * 73728;
    const unsigned short* Vg = vn + (size_t)nh * 73728;

    bf16x8 qf = *(const bf16x8*)(Qg + (size_t)(qt * 64 + wq * 16 + ln) * 32 + quad * 8);
    bf16x8 ones;
#pragma unroll
    for (int i = 0; i < 8; ++i) ones[i] = (short)0x3F80;

    f32x4 o0 = {0.f, 0.f, 0.f, 0.f};
    f32x4 o1 = {0.f, 0.f, 0.f, 0.f};
    f32x4 lac = {0.f, 0.f, 0.f, 0.f};

    int s0 = kz * 18 * 64;

    auto compute_tile = [&](int bsel) {
        const f32x4 zero = {0.f, 0.f, 0.f, 0.f};
        unsigned w[4][2];
#pragma unroll
        for (int c = 0; c < 4; ++c) {
            bf16x8 kf = *(const bf16x8*)(&Ks[bsel][c * 16 + ln][quad * 8]);
            // swapped: lane holds S[q=ln][k=c*16+quad*4+r]
            f32x4 sc = __builtin_amdgcn_mfma_f32_16x16x32_bf16(kf, qf, zero, 0, 0, 0);
            w[c][0] = cvt_pk_bf16(exp2f(sc[0]), exp2f(sc[1]));
            w[c][1] = cvt_pk_bf16(exp2f(sc[2]), exp2f(sc[3]));
        }
#pragma unroll
        for (int kc = 0; kc < 2; ++kc) {
            unsigned a0 = w[2 * kc][0], b0 = w[2 * kc + 1][0];
            permlane32_swap(a0, b0);
            permlane16_swap(a0, b0);
            unsigned a1 = w[2 * kc][1], b1 = w[2 * kc + 1][1];
            permlane32_swap(a1, b1);
            permlane16_swap(a1, b1);
            union { unsigned u[4]; bf16x8 v8; } pk;
            pk.u[0] = a0; pk.u[1] = a1; pk.u[2] = b0; pk.u[3] = b1;
            bf16x8 v0 = *(const bf16x8*)(&Vs[bsel][ln][kc * 32 + quad * 8]);
            bf16x8 v1 = *(const bf16x8*)(&Vs[bsel][16 + ln][kc * 32 + quad * 8]);
            lac = __builtin_amdgcn_mfma_f32_16x16x32_bf16(pk.v8, ones, lac, 0, 0, 0);
            o0  = __builtin_amdgcn_mfma_f32_16x16x32_bf16(pk.v8, v0, o0, 0, 0, 0);
            o1  = __builtin_amdgcn_mfma_f32_16x16x32_bf16(pk.v8, v1, o1, 0, 0, 0);
        }
    };

    // prologue: tile 0 -> LDS buf0; tile 1 -> regs B
    uint4 kA = *(const uint4*)(Kg + (size_t)s0 * 32 + tid * 8);
    uint4 vA = *(const uint4*)(Vg + (size_t)(tid >> 3) * SEQ + s0 + (tid & 7) * 8);
    *(uint4*)(&Ks[0][tid >> 2][(tid & 3) * 8]) = kA;
    *(uint4*)(&Vs[0][tid >> 3][(tid & 7) * 8]) = vA;
    uint4 kB = *(const uint4*)(Kg + (size_t)(s0 + 64) * 32 + tid * 8);
    uint4 vB = *(const uint4*)(Vg + (size_t)(tid >> 3) * SEQ + (s0 + 64) + (tid & 7) * 8);

    for (int i = 0; i < 18; i += 2) {
        // even iter: prefetch tile i+2 -> A; compute buf0 (tile i); write buf1 <- B (tile i+1)
        if (i + 2 < 18) {
            int sn = s0 + (i + 2) * 64;
            kA = *(const uint4*)(Kg + (size_t)sn * 32 + tid * 8);
            vA = *(const uint4*)(Vg + (size_t)(tid >> 3) * SEQ + sn + (tid & 7) * 8);
        }
        __syncthreads();
        compute_tile(0);
        *(uint4*)(&Ks[1][tid >> 2][(tid & 3) * 8]) = kB;
        *(uint4*)(&Vs[1][tid >> 3][(tid & 7) * 8]) = vB;
        // odd iter: prefetch tile i+3 -> B; compute buf1 (tile i+1); write buf0 <- A (tile i+2)
        if (i + 3 < 18) {
            int sn = s0 + (i + 3) * 64;
            kB = *(const uint4*)(Kg + (size_t)sn * 32 + tid * 8);
            vB = *(const uint4*)(Vg + (size_t)(tid >> 3) * SEQ + sn + (tid & 7) * 8);
        }
        __syncthreads();
        compute_tile(1);
        if (i + 2 < 18) {
            *(uint4*)(&Ks[0][tid >> 2][(tid & 3) * 8]) = kA;
            *(uint4*)(&Vs[0][tid >> 3][(tid & 7) * 8]) = vA;
        }
    }

    // epilogue: write f32 partials (lac[r] is the row-sum for the same q-row as o0[r]/o1[r])
    float* Ob = Opart + ((size_t)(kz * 16 + nh) * 36 + qt) * 2048;
    float* Lb = Lpart + ((size_t)(kz * 16 + nh) * 36 + qt) * 64;
#pragma unroll
    for (int r = 0; r < 4; ++r) {
        int ql = wq * 16 + quad * 4 + r;
        Ob[ql * 32 + ln]      = o0[r];
        Ob[ql * 32 + 16 + ln] = o1[r];
        if (ln == 0) Lb[ql] = lac[r];
    }
}

// ---------------- Kernel 4: split-K reduce -> y2t[n][s][c] bf16 (vectorized) ----------------
__global__ __launch_bounds__(256) void attn_reduce_kernel(const float* __restrict__ Opart,
                                                          const float* __restrict__ Lpart,
                                                          unsigned short* __restrict__ y2t) {
    int qt = blockIdx.x, nh = blockIdx.y;
    int n = nh >> 3, h = nh & 7;
    size_t s0 = (size_t)nh * 36 + qt;
    const float* O0 = Opart + s0 * 2048;
    const float* O1 = Opart + (s0 + 16 * 36) * 2048;
    const float* L0 = Lpart + s0 * 64;
    const float* L1 = Lpart + (s0 + 16 * 36) * 64;
#pragma unroll
    for (int p = 0; p < 2; ++p) {
        int idx = (threadIdx.x + p * 256) * 4;       // 0..2044, step 4
        int q = idx >> 5, c = idx & 31;
        float inv = 1.0f / (L0[q] + L1[q]);
        float4 a = *(const float4*)&O0[idx];
        float4 b = *(const float4*)&O1[idx];
        float r0 = (a.x + b.x) * inv;
        float r1 = (a.y + b.y) * inv;
        float r2 = (a.z + b.z) * inv;
        float r3 = (a.w + b.w) * inv;
        *(uint2*)&y2t[((size_t)(n * SEQ) + qt * 64 + q) * 256 + h * 32 + c] =
            make_uint2(cvt_pk_bf16(r0, r1), cvt_pk_bf16(r2, r3));
    }
}

// ---------------- Kernel 5: out GEMM (bf16 MFMA, LDS-free) + residual (unchanged) ----------------
__global__ __launch_bounds__(256) void out_gemm_kernel(const unsigned short* __restrict__ y2t,
                                                       const unsigned short* __restrict__ wob,
                                                       const float* __restrict__ x,
                                                       float* __restrict__ out) {
    int st = blockIdx.x;   // 0..71
    int mt = blockIdx.y;   // 0..3
    int n  = blockIdx.z;
    int tid = threadIdx.x;
    int wave = tid >> 6, lane = tid & 63;
    int ln = lane & 15, quad = lane >> 4;
    int m0 = mt * 64 + wave * 16;
    const unsigned short* Abase = wob + (size_t)(m0 + ln) * 256 + quad * 8;
    const unsigned short* Bbase = y2t + (size_t)(n * SEQ + st * 32 + ln) * 256 + quad * 8;
    f32x4 acc[2];
#pragma unroll
    for (int c = 0; c < 2; ++c) acc[c] = (f32x4){0.f, 0.f, 0.f, 0.f};
#pragma unroll
    for (int kc = 0; kc < 8; ++kc) {
        bf16x8 a = *(const bf16x8*)(Abase + kc * 32);
#pragma unroll
        for (int c = 0; c < 2; ++c) {
            bf16x8 b = *(const bf16x8*)(Bbase + (size_t)(c * 16) * 256 + kc * 32);
            acc[c] = __builtin_amdgcn_mfma_f32_16x16x32_bf16(a, b, acc[c], 0, 0, 0);
        }
    }
    const float c0f = 0.7f * 1.3130643285972254f;
    const float c1f = 0.3f * 1.3130643285972254f;
#pragma unroll
    for (int c = 0; c < 2; ++c)
#pragma unroll
        for (int r = 0; r < 4; ++r) {
            int o = m0 + quad * 4 + r;
            int s = st * 32 + c * 16 + ln;
            size_t idx = (size_t)(n * 256 + o) * SEQ + s;
            out[idx] = c0f * x[idx] + c1f * acc[c][r];
        }
}

extern "C" void kernel_launch(void* const* d_in, const int* in_sizes, int n_in,
                              void* d_out, int out_size, void* d_ws, size_t ws_size,
                              hipStream_t stream) {
    (void)in_sizes; (void)n_in; (void)out_size; (void)ws_size;
    const float* x     = (const float*)d_in[0];
    const float* w_qkv = (const float*)d_in[1];
    const float* w_out = (const float*)d_in[2];
    float* out = (float*)d_out;
    float* ws  = (float*)d_ws;
    unsigned short* wqb = (unsigned short*)(ws);             // 98304 f
    unsigned short* wob = (unsigned short*)(ws + 98304);     // 32768 f
    unsigned short* xt  = (unsigned short*)(ws + 131072);    // 589824 f (dead after qkv)
    unsigned short* y2t = (unsigned short*)(ws + 131072);    // alias of xt
    unsigned short* qn  = (unsigned short*)(ws + 720896);
    unsigned short* kn  = (unsigned short*)(ws + 1310720);
    unsigned short* vn  = (unsigned short*)(ws + 1900544);
    float* Opart = ws + 2490368;                             // 32*36*2048 = 2359296 f
    float* Lpart = ws + 4849664;                             // 32*36*64   =   73728 f

    hipLaunchKernelGGL(prep_kernel, dim3(1408), dim3(256), 0, stream,
                       w_qkv, w_out, x, wqb, wob, xt);
    hipLaunchKernelGGL(qkv_fused_kernel, dim3(576), dim3(256), 0, stream,
                       xt, wqb, qn, kn, vn);
    hipLaunchKernelGGL(attn_mfma_kernel, dim3(1152), dim3(256), 0, stream,
                       qn, kn, vn, Opart, Lpart);
    hipLaunchKernelGGL(attn_reduce_kernel, dim3(36, 16), dim3(256), 0, stream,
                       Opart, Lpart, y2t);
    hipLaunchKernelGGL(out_gemm_kernel, dim3(72, 4, 2), dim3(256), 0, stream,
                       y2t, wob, x, out);
}

// Round 7
// 129.949 us; speedup vs baseline: 1.0374x; 1.0366x over previous
//
#include <hip/hip_runtime.h>
#include <math.h>

#define EPSN 1e-4f
#define SEQ 2304

using bf16x8 = __attribute__((ext_vector_type(8))) short;
using f32x4  = __attribute__((ext_vector_type(4))) float;

__device__ inline unsigned short f2bf(float x) {
    union { float f; unsigned u; } c; c.f = x;
    unsigned u = c.u;
    u += 0x7fffu + ((u >> 16) & 1u);
    return (unsigned short)(u >> 16);
}

// HW packed f32->bf16 (RNE), gfx950.
__device__ inline unsigned cvt_pk_bf16(float lo, float hi) {
    unsigned r;
    asm("v_cvt_pk_bf16_f32 %0, %1, %2" : "=v"(r) : "v"(lo), "v"(hi));
    return r;
}
// gfx950 cross-row swaps (verified passing in R3/R4/R5).
__device__ inline void permlane32_swap(unsigned &a, unsigned &b) {
    asm("v_permlane32_swap_b32 %0, %1" : "+v"(a), "+v"(b));
}
__device__ inline void permlane16_swap(unsigned &a, unsigned &b) {
    asm("v_permlane16_swap_b32 %0, %1" : "+v"(a), "+v"(b));
}

// ---------------- Kernel 1: prep = weight-norm (blocks 0..255) + x-transpose ----------------
__global__ __launch_bounds__(256) void prep_kernel(const float* __restrict__ w_qkv,
                                                   const float* __restrict__ w_out,
                                                   const float* __restrict__ x,
                                                   unsigned short* __restrict__ wqb,
                                                   unsigned short* __restrict__ wob,
                                                   unsigned short* __restrict__ xt) {
    __shared__ __align__(16) unsigned short T[16][72];
    int bid = blockIdx.x;
    if (bid < 256) {
        int wave = threadIdx.x >> 6, lane = threadIdx.x & 63;
        int row = bid * 4 + wave;
        const float* src;
        unsigned short* dst;
        if (row < 768) { src = w_qkv + (size_t)row * 256; dst = wqb + (size_t)row * 256; }
        else           { src = w_out + (size_t)(row - 768) * 256; dst = wob + (size_t)(row - 768) * 256; }
        float4 v = *(const float4*)&src[lane * 4];
        float ss = v.x * v.x + v.y * v.y + v.z * v.z + v.w * v.w;
        for (int off = 32; off > 0; off >>= 1) ss += __shfl_xor(ss, off, 64);
        float sc = 1.0f / (sqrtf(ss) + 16.0f * EPSN);
        unsigned p0 = (unsigned)f2bf(v.x * sc) | ((unsigned)f2bf(v.y * sc) << 16);
        unsigned p1 = (unsigned)f2bf(v.z * sc) | ((unsigned)f2bf(v.w * sc) << 16);
        *(uint2*)&dst[lane * 4] = make_uint2(p0, p1);
    } else {
        // transpose x[n][c][s] -> xt[n][s][c] bf16; unit = 64c x 16s (1152 blocks)
        int e0 = bid - 256;            // 0..1151
        int n = e0 / 576;
        int r = e0 % 576;
        int ct = r / 144;
        int r2 = r % 144;
        int st = r2 >> 2, sq = r2 & 3;
        int tid = threadIdx.x;
        int c = tid >> 2, sv = (tid & 3) * 4;
        float4 v = *(const float4*)&x[(size_t)(n * 256 + ct * 64 + c) * SEQ + st * 64 + sq * 16 + sv];
        T[sv + 0][c] = f2bf(v.x);
        T[sv + 1][c] = f2bf(v.y);
        T[sv + 2][c] = f2bf(v.z);
        T[sv + 3][c] = f2bf(v.w);
        __syncthreads();
        int s = tid >> 4, cb = (tid & 15) * 4;
        uint2 t2 = *(const uint2*)&T[s][cb];
        *(uint2*)&xt[(size_t)(n * SEQ + st * 64 + sq * 16 + s) * 256 + ct * 64 + cb] = t2;
    }
}

// ---------------- Kernel 2: fused QKV GEMM + d-normalize, 32-s tiles (1152 blocks) ----------------
// Each block: one head's 96 outputs x 32 s. 4 waves = 2 s-groups x 2 m-groups (48 rows).
// XCD-bijective: each XCD owns 18 (st2,n) half-tiles for all 8 heads.
__global__ __launch_bounds__(256) void qkv_fused_kernel(const unsigned short* __restrict__ xt,
                                                        const unsigned short* __restrict__ wqb,
                                                        unsigned short* __restrict__ qn,
                                                        unsigned short* __restrict__ kn,
                                                        unsigned short* __restrict__ vn) {
    __shared__ float Cs[96][33];
    __shared__ __align__(16) unsigned short Vls[32][40];
    int bid = blockIdx.x;                   // 0..1151
    int xcd = bid & 7, j = bid >> 3;        // j 0..143
    int h = j & 7;
    int tile = xcd * 18 + (j >> 3);         // 0..143
    int st2 = tile % 72, n = tile / 72;     // 32-s tile, batch
    int tid = threadIdx.x;
    int wave = tid >> 6, lane = tid & 63;
    int ln = lane & 15, quad = lane >> 4;
    int sgrp = wave & 1, mgrp = wave >> 1;
    const unsigned short* Abase = wqb + (size_t)(h * 96 + mgrp * 48 + ln) * 256 + quad * 8;
    const unsigned short* Bbase = xt + (size_t)(n * SEQ + st2 * 32 + sgrp * 16 + ln) * 256 + quad * 8;
    f32x4 acc[3];
#pragma unroll
    for (int m = 0; m < 3; ++m) acc[m] = (f32x4){0.f, 0.f, 0.f, 0.f};
#pragma unroll
    for (int kc = 0; kc < 8; ++kc) {
        bf16x8 b = *(const bf16x8*)(Bbase + kc * 32);
#pragma unroll
        for (int m = 0; m < 3; ++m) {
            bf16x8 a = *(const bf16x8*)(Abase + (size_t)(m * 16) * 256 + kc * 32);
            acc[m] = __builtin_amdgcn_mfma_f32_16x16x32_bf16(a, b, acc[m], 0, 0, 0);
        }
    }
#pragma unroll
    for (int m = 0; m < 3; ++m)
#pragma unroll
        for (int r = 0; r < 4; ++r)
            Cs[mgrp * 48 + m * 16 + quad * 4 + r][sgrp * 16 + ln] = acc[m][r];
    __syncthreads();
    int nh = n * 8 + h;
    if (tid < 96) {
        int sl = tid & 31, wh = tid >> 5;
        int s = st2 * 32 + sl;
        float v[32];
        float ss = 0.f;
#pragma unroll
        for (int d = 0; d < 32; ++d) { v[d] = Cs[3 * d + wh][sl]; ss += v[d] * v[d]; }
        float inv = 1.0f / (EPSN + sqrtf(ss * (1.0f / 32.0f)));
        // fold softmax scale (1/sqrt(32)) AND log2(e) into q so attn uses exp2
        if (wh == 0) inv *= 0.17677669529663687f * 1.4426950408889634f;
        if (wh == 2) {
#pragma unroll
            for (int d = 0; d < 32; ++d) Vls[d][sl] = f2bf(v[d] * inv);
        } else {
            unsigned short* dst = (wh == 1 ? kn : qn) + (size_t)nh * 73728 + (size_t)s * 32;
            unsigned wbuf[16];
#pragma unroll
            for (int j2 = 0; j2 < 16; ++j2)
                wbuf[j2] = (unsigned)f2bf(v[2 * j2] * inv) | ((unsigned)f2bf(v[2 * j2 + 1] * inv) << 16);
#pragma unroll
            for (int j2 = 0; j2 < 4; ++j2) {
                uint4 t4 = make_uint4(wbuf[4 * j2], wbuf[4 * j2 + 1], wbuf[4 * j2 + 2], wbuf[4 * j2 + 3]);
                *(uint4*)(dst + j2 * 8) = t4;
            }
        }
    }
    __syncthreads();
    {
        int d = tid >> 3, sj = (tid & 7) * 4;
        uint2 t2 = *(const uint2*)&Vls[d][sj];
        *(uint2*)&vn[(size_t)nh * 73728 + (size_t)d * SEQ + st2 * 32 + sj] = t2;
    }
}

// ---------------- Kernel 3: MFMA flash attention, split-K=4 ACROSS blocks (2304 blocks) ----------------
// 256 thr = 4 waves (one q-subtile each), 9 k-tiles per block, 19.5KB LDS,
// 2-deep register staging, permlane P-redistribute, ones-MFMA row-sum.
__global__ __launch_bounds__(256) void attn_mfma_kernel(const unsigned short* __restrict__ qn,
                                                        const unsigned short* __restrict__ kn,
                                                        const unsigned short* __restrict__ vn,
                                                        float* __restrict__ Opart,
                                                        float* __restrict__ Lpart) {
    __shared__ __align__(16) unsigned short Ks[2][64][40];
    __shared__ __align__(16) unsigned short Vs[2][32][72];
    int tid = threadIdx.x;
    int wq = tid >> 6, lane = tid & 63;
    int ln = lane & 15, quad = lane >> 4;
    // XCD swizzle: 2304 = 8 * 288; each XCD owns 2 heads (all kz, all qt)
    int bid = blockIdx.x;
    int xcd = bid & 7, bi = bid >> 3;       // bi 0..287
    int nh = xcd * 2 + (bi >= 144);
    int bi2 = (bi >= 144) ? bi - 144 : bi;  // 0..143
    int qt = bi2 % 36, kz = bi2 / 36;       // kz 0..3
    const unsigned short* Qg = qn + (size_t)nh * 73728;
    const unsigned short* Kg = kn + (size_t)nh * 73728;
    const unsigned short* Vg = vn + (size_t)nh * 73728;

    bf16x8 qf = *(const bf16x8*)(Qg + (size_t)(qt * 64 + wq * 16 + ln) * 32 + quad * 8);
    bf16x8 ones;
#pragma unroll
    for (int i = 0; i < 8; ++i) ones[i] = (short)0x3F80;

    f32x4 o0 = {0.f, 0.f, 0.f, 0.f};
    f32x4 o1 = {0.f, 0.f, 0.f, 0.f};
    f32x4 lac = {0.f, 0.f, 0.f, 0.f};

    const int NT = 9;
    int s0 = kz * NT * 64;

    auto compute_tile = [&](int bsel) {
        const f32x4 zero = {0.f, 0.f, 0.f, 0.f};
        unsigned w[4][2];
#pragma unroll
        for (int c = 0; c < 4; ++c) {
            bf16x8 kf = *(const bf16x8*)(&Ks[bsel][c * 16 + ln][quad * 8]);
            // swapped: lane holds S[q=ln][k=c*16+quad*4+r]
            f32x4 sc = __builtin_amdgcn_mfma_f32_16x16x32_bf16(kf, qf, zero, 0, 0, 0);
            w[c][0] = cvt_pk_bf16(exp2f(sc[0]), exp2f(sc[1]));
            w[c][1] = cvt_pk_bf16(exp2f(sc[2]), exp2f(sc[3]));
        }
#pragma unroll
        for (int kc = 0; kc < 2; ++kc) {
            unsigned a0 = w[2 * kc][0], b0 = w[2 * kc + 1][0];
            permlane32_swap(a0, b0);
            permlane16_swap(a0, b0);
            unsigned a1 = w[2 * kc][1], b1 = w[2 * kc + 1][1];
            permlane32_swap(a1, b1);
            permlane16_swap(a1, b1);
            union { unsigned u[4]; bf16x8 v8; } pk;
            pk.u[0] = a0; pk.u[1] = a1; pk.u[2] = b0; pk.u[3] = b1;
            bf16x8 v0 = *(const bf16x8*)(&Vs[bsel][ln][kc * 32 + quad * 8]);
            bf16x8 v1 = *(const bf16x8*)(&Vs[bsel][16 + ln][kc * 32 + quad * 8]);
            lac = __builtin_amdgcn_mfma_f32_16x16x32_bf16(pk.v8, ones, lac, 0, 0, 0);
            o0  = __builtin_amdgcn_mfma_f32_16x16x32_bf16(pk.v8, v0, o0, 0, 0, 0);
            o1  = __builtin_amdgcn_mfma_f32_16x16x32_bf16(pk.v8, v1, o1, 0, 0, 0);
        }
    };

    // prologue: tile 0 -> LDS buf0; tile 1 -> regs B (NT >= 2 always)
    uint4 kA = *(const uint4*)(Kg + (size_t)s0 * 32 + tid * 8);
    uint4 vA = *(const uint4*)(Vg + (size_t)(tid >> 3) * SEQ + s0 + (tid & 7) * 8);
    *(uint4*)(&Ks[0][tid >> 2][(tid & 3) * 8]) = kA;
    *(uint4*)(&Vs[0][tid >> 3][(tid & 7) * 8]) = vA;
    uint4 kB = *(const uint4*)(Kg + (size_t)(s0 + 64) * 32 + tid * 8);
    uint4 vB = *(const uint4*)(Vg + (size_t)(tid >> 3) * SEQ + (s0 + 64) + (tid & 7) * 8);

    for (int i = 0; i < NT; i += 2) {
        // even iter: prefetch tile i+2 -> A; compute buf0 (tile i); write buf1 <- B (tile i+1)
        if (i + 2 < NT) {
            int sn = s0 + (i + 2) * 64;
            kA = *(const uint4*)(Kg + (size_t)sn * 32 + tid * 8);
            vA = *(const uint4*)(Vg + (size_t)(tid >> 3) * SEQ + sn + (tid & 7) * 8);
        }
        __syncthreads();
        compute_tile(0);
        if (i + 1 < NT) {
            *(uint4*)(&Ks[1][tid >> 2][(tid & 3) * 8]) = kB;
            *(uint4*)(&Vs[1][tid >> 3][(tid & 7) * 8]) = vB;
        }
        // odd iter: prefetch tile i+3 -> B; compute buf1 (tile i+1); write buf0 <- A (tile i+2)
        if (i + 3 < NT) {
            int sn = s0 + (i + 3) * 64;
            kB = *(const uint4*)(Kg + (size_t)sn * 32 + tid * 8);
            vB = *(const uint4*)(Vg + (size_t)(tid >> 3) * SEQ + sn + (tid & 7) * 8);
        }
        __syncthreads();
        if (i + 1 < NT) compute_tile(1);
        if (i + 2 < NT) {
            *(uint4*)(&Ks[0][tid >> 2][(tid & 3) * 8]) = kA;
            *(uint4*)(&Vs[0][tid >> 3][(tid & 7) * 8]) = vA;
        }
    }

    // epilogue: write f32 partials (lac[r] is the row-sum for the same q-row as o0[r]/o1[r])
    float* Ob = Opart + ((size_t)(kz * 16 + nh) * 36 + qt) * 2048;
    float* Lb = Lpart + ((size_t)(kz * 16 + nh) * 36 + qt) * 64;
#pragma unroll
    for (int r = 0; r < 4; ++r) {
        int ql = wq * 16 + quad * 4 + r;
        Ob[ql * 32 + ln]      = o0[r];
        Ob[ql * 32 + 16 + ln] = o1[r];
        if (ln == 0) Lb[ql] = lac[r];
    }
}

// ---------------- Kernel 4: split-K=4 reduce -> y2t[n][s][c] bf16 (vectorized) ----------------
__global__ __launch_bounds__(256) void attn_reduce_kernel(const float* __restrict__ Opart,
                                                          const float* __restrict__ Lpart,
                                                          unsigned short* __restrict__ y2t) {
    int qt = blockIdx.x, nh = blockIdx.y;
    int n = nh >> 3, h = nh & 7;
    size_t s0 = (size_t)nh * 36 + qt;
    const float* O0 = Opart + s0 * 2048;
    const float* O1 = Opart + (s0 + 1 * 576) * 2048;
    const float* O2 = Opart + (s0 + 2 * 576) * 2048;
    const float* O3 = Opart + (s0 + 3 * 576) * 2048;
    const float* L0 = Lpart + s0 * 64;
    const float* L1 = Lpart + (s0 + 1 * 576) * 64;
    const float* L2 = Lpart + (s0 + 2 * 576) * 64;
    const float* L3 = Lpart + (s0 + 3 * 576) * 64;
#pragma unroll
    for (int p = 0; p < 2; ++p) {
        int idx = (threadIdx.x + p * 256) * 4;       // 0..2044, step 4
        int q = idx >> 5, c = idx & 31;
        float inv = 1.0f / (L0[q] + L1[q] + L2[q] + L3[q]);
        float4 a = *(const float4*)&O0[idx];
        float4 b = *(const float4*)&O1[idx];
        float4 e = *(const float4*)&O2[idx];
        float4 f = *(const float4*)&O3[idx];
        float r0 = ((a.x + b.x) + (e.x + f.x)) * inv;
        float r1 = ((a.y + b.y) + (e.y + f.y)) * inv;
        float r2 = ((a.z + b.z) + (e.z + f.z)) * inv;
        float r3 = ((a.w + b.w) + (e.w + f.w)) * inv;
        *(uint2*)&y2t[((size_t)(n * SEQ) + qt * 64 + q) * 256 + h * 32 + c] =
            make_uint2(cvt_pk_bf16(r0, r1), cvt_pk_bf16(r2, r3));
    }
}

// ---------------- Kernel 5: out GEMM, 16-s tiles (1152 blocks) + residual ----------------
// XCD swizzle: the 4 mt-blocks sharing a y2t B-tile land on the same XCD;
// each XCD owns an 18-wide contiguous s range for both n.
__global__ __launch_bounds__(256) void out_gemm_kernel(const unsigned short* __restrict__ y2t,
                                                       const unsigned short* __restrict__ wob,
                                                       const float* __restrict__ x,
                                                       float* __restrict__ out) {
    int bid = blockIdx.x;                  // 0..1151
    int xcd = bid & 7, j = bid >> 3;       // 0..143
    int mt = j & 3;
    int u = j >> 2;                        // 0..35
    int n = u & 1;
    int st = xcd * 18 + (u >> 1);          // 0..143 (16-s tiles)
    int tid = threadIdx.x;
    int wave = tid >> 6, lane = tid & 63;
    int ln = lane & 15, quad = lane >> 4;
    int m0 = mt * 64 + wave * 16;
    const unsigned short* Abase = wob + (size_t)(m0 + ln) * 256 + quad * 8;
    const unsigned short* Bbase = y2t + (size_t)(n * SEQ + st * 16 + ln) * 256 + quad * 8;
    f32x4 acc = (f32x4){0.f, 0.f, 0.f, 0.f};
#pragma unroll
    for (int kc = 0; kc < 8; ++kc) {
        bf16x8 a = *(const bf16x8*)(Abase + kc * 32);
        bf16x8 b = *(const bf16x8*)(Bbase + kc * 32);
        acc = __builtin_amdgcn_mfma_f32_16x16x32_bf16(a, b, acc, 0, 0, 0);
    }
    const float c0f = 0.7f * 1.3130643285972254f;
    const float c1f = 0.3f * 1.3130643285972254f;
#pragma unroll
    for (int r = 0; r < 4; ++r) {
        int o = m0 + quad * 4 + r;
        int s = st * 16 + ln;
        size_t idx = (size_t)(n * 256 + o) * SEQ + s;
        out[idx] = c0f * x[idx] + c1f * acc[r];
    }
}

extern "C" void kernel_launch(void* const* d_in, const int* in_sizes, int n_in,
                              void* d_out, int out_size, void* d_ws, size_t ws_size,
                              hipStream_t stream) {
    (void)in_sizes; (void)n_in; (void)out_size; (void)ws_size;
    const float* x     = (const float*)d_in[0];
    const float* w_qkv = (const float*)d_in[1];
    const float* w_out = (const float*)d_in[2];
    float* out = (float*)d_out;
    float* ws  = (float*)d_ws;
    unsigned short* wqb = (unsigned short*)(ws);             // 98304 f
    unsigned short* wob = (unsigned short*)(ws + 98304);     // 32768 f
    unsigned short* xt  = (unsigned short*)(ws + 131072);    // 589824 f (dead after qkv)
    unsigned short* y2t = (unsigned short*)(ws + 131072);    // alias of xt
    unsigned short* qn  = (unsigned short*)(ws + 720896);
    unsigned short* kn  = (unsigned short*)(ws + 1310720);
    unsigned short* vn  = (unsigned short*)(ws + 1900544);
    float* Opart = ws + 2490368;                             // 64*36*2048 = 4718592 f
    float* Lpart = ws + 7208960;                             // 64*36*64   =  147456 f

    hipLaunchKernelGGL(prep_kernel, dim3(1408), dim3(256), 0, stream,
                       w_qkv, w_out, x, wqb, wob, xt);
    hipLaunchKernelGGL(qkv_fused_kernel, dim3(1152), dim3(256), 0, stream,
                       xt, wqb, qn, kn, vn);
    hipLaunchKernelGGL(attn_mfma_kernel, dim3(2304), dim3(256), 0, stream,
                       qn, kn, vn, Opart, Lpart);
    hipLaunchKernelGGL(attn_reduce_kernel, dim3(36, 16), dim3(256), 0, stream,
                       Opart, Lpart, y2t);
    hipLaunchKernelGGL(out_gemm_kernel, dim3(1152), dim3(256), 0, stream,
                       y2t, wob, x, out);
}

// Round 8
// 123.293 us; speedup vs baseline: 1.0934x; 1.0540x over previous
//
#include <hip/hip_runtime.h>
#include <math.h>

#define EPSN 1e-4f
#define SEQ 2304

using bf16x8 = __attribute__((ext_vector_type(8))) short;
using f32x4  = __attribute__((ext_vector_type(4))) float;

__device__ inline unsigned short f2bf(float x) {
    union { float f; unsigned u; } c; c.f = x;
    unsigned u = c.u;
    u += 0x7fffu + ((u >> 16) & 1u);
    return (unsigned short)(u >> 16);
}

// HW packed f32->bf16 (RNE), gfx950.
__device__ inline unsigned cvt_pk_bf16(float lo, float hi) {
    unsigned r;
    asm("v_cvt_pk_bf16_f32 %0, %1, %2" : "=v"(r) : "v"(lo), "v"(hi));
    return r;
}
// gfx950 cross-row swaps (verified passing R3-R7).
__device__ inline void permlane32_swap(unsigned &a, unsigned &b) {
    asm("v_permlane32_swap_b32 %0, %1" : "+v"(a), "+v"(b));
}
__device__ inline void permlane16_swap(unsigned &a, unsigned &b) {
    asm("v_permlane16_swap_b32 %0, %1" : "+v"(a), "+v"(b));
}

// ---------------- Kernel 1: weight-norm only (256 blocks) ----------------
__global__ __launch_bounds__(256) void prep_w_kernel(const float* __restrict__ w_qkv,
                                                     const float* __restrict__ w_out,
                                                     unsigned short* __restrict__ wqb,
                                                     unsigned short* __restrict__ wob) {
    int wave = threadIdx.x >> 6, lane = threadIdx.x & 63;
    int row = blockIdx.x * 4 + wave;
    const float* src;
    unsigned short* dst;
    if (row < 768) { src = w_qkv + (size_t)row * 256; dst = wqb + (size_t)row * 256; }
    else           { src = w_out + (size_t)(row - 768) * 256; dst = wob + (size_t)(row - 768) * 256; }
    float4 v = *(const float4*)&src[lane * 4];
    float ss = v.x * v.x + v.y * v.y + v.z * v.z + v.w * v.w;
    for (int off = 32; off > 0; off >>= 1) ss += __shfl_xor(ss, off, 64);
    float sc = 1.0f / (sqrtf(ss) + 16.0f * EPSN);
    unsigned p0 = (unsigned)f2bf(v.x * sc) | ((unsigned)f2bf(v.y * sc) << 16);
    unsigned p1 = (unsigned)f2bf(v.z * sc) | ((unsigned)f2bf(v.w * sc) << 16);
    *(uint2*)&dst[lane * 4] = make_uint2(p0, p1);
}

// ---------------- Kernel 2: fused x-transpose + QKV GEMM + d-normalize (1152 blocks) ----------------
// Block = one head x one (n, 32-s) tile. Loads its x tile [256c x 32s] f32 directly
// (xt buffer eliminated), transposes to bf16 in LDS, then the verified MFMA+norm path.
// XCD-bijective: 8 head-siblings of a tile land on one XCD -> x tile fetched once/L2.
__global__ __launch_bounds__(256) void qkv_fused_kernel(const float* __restrict__ x,
                                                        const unsigned short* __restrict__ wqb,
                                                        unsigned short* __restrict__ qn,
                                                        unsigned short* __restrict__ kn,
                                                        unsigned short* __restrict__ vn) {
    __shared__ __align__(16) unsigned short Xs[32][264];
    __shared__ float Cs[96][33];
    __shared__ __align__(16) unsigned short Vls[32][40];
    int bid = blockIdx.x;                   // 0..1151
    int xcd = bid & 7, j = bid >> 3;        // j 0..143
    int h = j & 7;
    int tile = xcd * 18 + (j >> 3);         // 0..143
    int st2 = tile % 72, n = tile / 72;     // 32-s tile, batch
    int tid = threadIdx.x;
    int wave = tid >> 6, lane = tid & 63;
    int ln = lane & 15, quad = lane >> 4;
    int sgrp = wave & 1, mgrp = wave >> 1;
    int s0 = st2 * 32;

    // stage x[n][c][s0..s0+31] -> Xs[s][c] bf16
    {
        int ci = tid >> 3, sv = (tid & 7) * 4;
#pragma unroll
        for (int p = 0; p < 8; ++p) {
            int c = p * 32 + ci;
            float4 v = *(const float4*)&x[(size_t)(n * 256 + c) * SEQ + s0 + sv];
            Xs[sv + 0][c] = f2bf(v.x);
            Xs[sv + 1][c] = f2bf(v.y);
            Xs[sv + 2][c] = f2bf(v.z);
            Xs[sv + 3][c] = f2bf(v.w);
        }
    }
    __syncthreads();

    const unsigned short* Abase = wqb + (size_t)(h * 96 + mgrp * 48 + ln) * 256 + quad * 8;
    f32x4 acc[3];
#pragma unroll
    for (int m = 0; m < 3; ++m) acc[m] = (f32x4){0.f, 0.f, 0.f, 0.f};
#pragma unroll
    for (int kc = 0; kc < 8; ++kc) {
        bf16x8 b = *(const bf16x8*)&Xs[sgrp * 16 + ln][kc * 32 + quad * 8];
#pragma unroll
        for (int m = 0; m < 3; ++m) {
            bf16x8 a = *(const bf16x8*)(Abase + (size_t)(m * 16) * 256 + kc * 32);
            acc[m] = __builtin_amdgcn_mfma_f32_16x16x32_bf16(a, b, acc[m], 0, 0, 0);
        }
    }
#pragma unroll
    for (int m = 0; m < 3; ++m)
#pragma unroll
        for (int r = 0; r < 4; ++r)
            Cs[mgrp * 48 + m * 16 + quad * 4 + r][sgrp * 16 + ln] = acc[m][r];
    __syncthreads();
    int nh = n * 8 + h;
    if (tid < 96) {
        int sl = tid & 31, wh = tid >> 5;
        int s = st2 * 32 + sl;
        float v[32];
        float ss = 0.f;
#pragma unroll
        for (int d = 0; d < 32; ++d) { v[d] = Cs[3 * d + wh][sl]; ss += v[d] * v[d]; }
        float inv = 1.0f / (EPSN + sqrtf(ss * (1.0f / 32.0f)));
        // fold softmax scale (1/sqrt(32)) AND log2(e) into q so attn uses exp2
        if (wh == 0) inv *= 0.17677669529663687f * 1.4426950408889634f;
        if (wh == 2) {
#pragma unroll
            for (int d = 0; d < 32; ++d) Vls[d][sl] = f2bf(v[d] * inv);
        } else {
            unsigned short* dst = (wh == 1 ? kn : qn) + (size_t)nh * 73728 + (size_t)s * 32;
            unsigned wbuf[16];
#pragma unroll
            for (int j2 = 0; j2 < 16; ++j2)
                wbuf[j2] = (unsigned)f2bf(v[2 * j2] * inv) | ((unsigned)f2bf(v[2 * j2 + 1] * inv) << 16);
#pragma unroll
            for (int j2 = 0; j2 < 4; ++j2) {
                uint4 t4 = make_uint4(wbuf[4 * j2], wbuf[4 * j2 + 1], wbuf[4 * j2 + 2], wbuf[4 * j2 + 3]);
                *(uint4*)(dst + j2 * 8) = t4;
            }
        }
    }
    __syncthreads();
    {
        int d = tid >> 3, sj = (tid & 7) * 4;
        uint2 t2 = *(const uint2*)&Vls[d][sj];
        *(uint2*)&vn[(size_t)nh * 73728 + (size_t)d * SEQ + st2 * 32 + sj] = t2;
    }
}

// ---------------- Kernel 3: MFMA flash attention, split-K=4 ACROSS blocks (2304 blocks) ----------------
// UNCHANGED from R7 (verified passing).
__global__ __launch_bounds__(256) void attn_mfma_kernel(const unsigned short* __restrict__ qn,
                                                        const unsigned short* __restrict__ kn,
                                                        const unsigned short* __restrict__ vn,
                                                        float* __restrict__ Opart,
                                                        float* __restrict__ Lpart) {
    __shared__ __align__(16) unsigned short Ks[2][64][40];
    __shared__ __align__(16) unsigned short Vs[2][32][72];
    int tid = threadIdx.x;
    int wq = tid >> 6, lane = tid & 63;
    int ln = lane & 15, quad = lane >> 4;
    int bid = blockIdx.x;
    int xcd = bid & 7, bi = bid >> 3;       // bi 0..287
    int nh = xcd * 2 + (bi >= 144);
    int bi2 = (bi >= 144) ? bi - 144 : bi;  // 0..143
    int qt = bi2 % 36, kz = bi2 / 36;       // kz 0..3
    const unsigned short* Qg = qn + (size_t)nh * 73728;
    const unsigned short* Kg = kn + (size_t)nh * 73728;
    const unsigned short* Vg = vn + (size_t)nh * 73728;

    bf16x8 qf = *(const bf16x8*)(Qg + (size_t)(qt * 64 + wq * 16 + ln) * 32 + quad * 8);
    bf16x8 ones;
#pragma unroll
    for (int i = 0; i < 8; ++i) ones[i] = (short)0x3F80;

    f32x4 o0 = {0.f, 0.f, 0.f, 0.f};
    f32x4 o1 = {0.f, 0.f, 0.f, 0.f};
    f32x4 lac = {0.f, 0.f, 0.f, 0.f};

    const int NT = 9;
    int s0 = kz * NT * 64;

    auto compute_tile = [&](int bsel) {
        const f32x4 zero = {0.f, 0.f, 0.f, 0.f};
        unsigned w[4][2];
#pragma unroll
        for (int c = 0; c < 4; ++c) {
            bf16x8 kf = *(const bf16x8*)(&Ks[bsel][c * 16 + ln][quad * 8]);
            f32x4 sc = __builtin_amdgcn_mfma_f32_16x16x32_bf16(kf, qf, zero, 0, 0, 0);
            w[c][0] = cvt_pk_bf16(exp2f(sc[0]), exp2f(sc[1]));
            w[c][1] = cvt_pk_bf16(exp2f(sc[2]), exp2f(sc[3]));
        }
#pragma unroll
        for (int kc = 0; kc < 2; ++kc) {
            unsigned a0 = w[2 * kc][0], b0 = w[2 * kc + 1][0];
            permlane32_swap(a0, b0);
            permlane16_swap(a0, b0);
            unsigned a1 = w[2 * kc][1], b1 = w[2 * kc + 1][1];
            permlane32_swap(a1, b1);
            permlane16_swap(a1, b1);
            union { unsigned u[4]; bf16x8 v8; } pk;
            pk.u[0] = a0; pk.u[1] = a1; pk.u[2] = b0; pk.u[3] = b1;
            bf16x8 v0 = *(const bf16x8*)(&Vs[bsel][ln][kc * 32 + quad * 8]);
            bf16x8 v1 = *(const bf16x8*)(&Vs[bsel][16 + ln][kc * 32 + quad * 8]);
            lac = __builtin_amdgcn_mfma_f32_16x16x32_bf16(pk.v8, ones, lac, 0, 0, 0);
            o0  = __builtin_amdgcn_mfma_f32_16x16x32_bf16(pk.v8, v0, o0, 0, 0, 0);
            o1  = __builtin_amdgcn_mfma_f32_16x16x32_bf16(pk.v8, v1, o1, 0, 0, 0);
        }
    };

    uint4 kA = *(const uint4*)(Kg + (size_t)s0 * 32 + tid * 8);
    uint4 vA = *(const uint4*)(Vg + (size_t)(tid >> 3) * SEQ + s0 + (tid & 7) * 8);
    *(uint4*)(&Ks[0][tid >> 2][(tid & 3) * 8]) = kA;
    *(uint4*)(&Vs[0][tid >> 3][(tid & 7) * 8]) = vA;
    uint4 kB = *(const uint4*)(Kg + (size_t)(s0 + 64) * 32 + tid * 8);
    uint4 vB = *(const uint4*)(Vg + (size_t)(tid >> 3) * SEQ + (s0 + 64) + (tid & 7) * 8);

    for (int i = 0; i < NT; i += 2) {
        if (i + 2 < NT) {
            int sn = s0 + (i + 2) * 64;
            kA = *(const uint4*)(Kg + (size_t)sn * 32 + tid * 8);
            vA = *(const uint4*)(Vg + (size_t)(tid >> 3) * SEQ + sn + (tid & 7) * 8);
        }
        __syncthreads();
        compute_tile(0);
        if (i + 1 < NT) {
            *(uint4*)(&Ks[1][tid >> 2][(tid & 3) * 8]) = kB;
            *(uint4*)(&Vs[1][tid >> 3][(tid & 7) * 8]) = vB;
        }
        if (i + 3 < NT) {
            int sn = s0 + (i + 3) * 64;
            kB = *(const uint4*)(Kg + (size_t)sn * 32 + tid * 8);
            vB = *(const uint4*)(Vg + (size_t)(tid >> 3) * SEQ + sn + (tid & 7) * 8);
        }
        __syncthreads();
        if (i + 1 < NT) compute_tile(1);
        if (i + 2 < NT) {
            *(uint4*)(&Ks[0][tid >> 2][(tid & 3) * 8]) = kA;
            *(uint4*)(&Vs[0][tid >> 3][(tid & 7) * 8]) = vA;
        }
    }

    float* Ob = Opart + ((size_t)(kz * 16 + nh) * 36 + qt) * 2048;
    float* Lb = Lpart + ((size_t)(kz * 16 + nh) * 36 + qt) * 64;
#pragma unroll
    for (int r = 0; r < 4; ++r) {
        int ql = wq * 16 + quad * 4 + r;
        Ob[ql * 32 + ln]      = o0[r];
        Ob[ql * 32 + 16 + ln] = o1[r];
        if (ln == 0) Lb[ql] = lac[r];
    }
}

// ---------------- Kernel 4: fused split-K reduce + out GEMM + residual (1152 blocks) ----------------
// Block = (mt, 16-s tile, n). Phase A: rebuild the 16s x 256c bf16 B-tile from
// Opart/Lpart (coalesced float2 reads; 4 mt-siblings share it via same-XCD L2).
// Phase B: the verified LDS-free MFMA + residual epilogue. y2t buffer eliminated.
__global__ __launch_bounds__(256) void out_gemm_kernel(const float* __restrict__ Opart,
                                                       const float* __restrict__ Lpart,
                                                       const unsigned short* __restrict__ wob,
                                                       const float* __restrict__ x,
                                                       float* __restrict__ out) {
    __shared__ float Linv[8][16];
    __shared__ __align__(16) unsigned short Ys[16][264];
    int bid = blockIdx.x;                  // 0..1151
    int xcd = bid & 7, j = bid >> 3;       // 0..143
    int mt = j & 3;
    int u = j >> 2;                        // 0..35
    int n = u & 1;
    int st = xcd * 18 + (u >> 1);          // 0..143 (16-s tiles)
    int qt = st >> 2;                      // 64-q tile
    int qo = (st & 3) * 16;                // offset within it
    int tid = threadIdx.x;

    // Phase A0: l sums
    if (tid < 128) {
        int h = tid >> 4, qi = tid & 15;
        size_t base = ((size_t)((n * 8 + h) * 36) + qt) * 64 + qo + qi;
        const size_t kzs = (size_t)16 * 36 * 64;
        float l = Lpart[base] + Lpart[base + kzs] + Lpart[base + 2 * kzs] + Lpart[base + 3 * kzs];
        Linv[h][qi] = 1.0f / l;
    }
    __syncthreads();
    // Phase A1: B-tile from Opart
    {
        int qi = tid >> 4, dp = tid & 15, d0 = dp * 2;
        const size_t kzs = (size_t)16 * 36 * 2048;
#pragma unroll
        for (int h = 0; h < 8; ++h) {
            size_t ob = ((size_t)((n * 8 + h) * 36) + qt) * 2048 + (size_t)(qo + qi) * 32 + d0;
            float2 a = *(const float2*)&Opart[ob];
            float2 b = *(const float2*)&Opart[ob + kzs];
            float2 e = *(const float2*)&Opart[ob + 2 * kzs];
            float2 f = *(const float2*)&Opart[ob + 3 * kzs];
            float li = Linv[h][qi];
            float r0 = ((a.x + b.x) + (e.x + f.x)) * li;
            float r1 = ((a.y + b.y) + (e.y + f.y)) * li;
            *(unsigned*)&Ys[qi][h * 32 + d0] = cvt_pk_bf16(r0, r1);
        }
    }
    __syncthreads();

    // Phase B: GEMM + residual
    int wave = tid >> 6, lane = tid & 63;
    int ln = lane & 15, quad = lane >> 4;
    int m0 = mt * 64 + wave * 16;
    const unsigned short* Abase = wob + (size_t)(m0 + ln) * 256 + quad * 8;
    f32x4 acc = (f32x4){0.f, 0.f, 0.f, 0.f};
#pragma unroll
    for (int kc = 0; kc < 8; ++kc) {
        bf16x8 a = *(const bf16x8*)(Abase + kc * 32);
        bf16x8 b = *(const bf16x8*)&Ys[ln][kc * 32 + quad * 8];
        acc = __builtin_amdgcn_mfma_f32_16x16x32_bf16(a, b, acc, 0, 0, 0);
    }
    const float c0f = 0.7f * 1.3130643285972254f;
    const float c1f = 0.3f * 1.3130643285972254f;
#pragma unroll
    for (int r = 0; r < 4; ++r) {
        int o = m0 + quad * 4 + r;
        int s = st * 16 + ln;
        size_t idx = (size_t)(n * 256 + o) * SEQ + s;
        out[idx] = c0f * x[idx] + c1f * acc[r];
    }
}

extern "C" void kernel_launch(void* const* d_in, const int* in_sizes, int n_in,
                              void* d_out, int out_size, void* d_ws, size_t ws_size,
                              hipStream_t stream) {
    (void)in_sizes; (void)n_in; (void)out_size; (void)ws_size;
    const float* x     = (const float*)d_in[0];
    const float* w_qkv = (const float*)d_in[1];
    const float* w_out = (const float*)d_in[2];
    float* out = (float*)d_out;
    float* ws  = (float*)d_ws;
    unsigned short* wqb = (unsigned short*)(ws);             // 98304 f
    unsigned short* wob = (unsigned short*)(ws + 98304);     // 32768 f
    unsigned short* qn  = (unsigned short*)(ws + 131072);    // 589824 f each
    unsigned short* kn  = (unsigned short*)(ws + 720896);
    unsigned short* vn  = (unsigned short*)(ws + 1310720);
    float* Opart = ws + 1900544;                             // 64*36*2048 = 4718592 f
    float* Lpart = ws + 6619136;                             // 64*36*64   =  147456 f

    hipLaunchKernelGGL(prep_w_kernel, dim3(256), dim3(256), 0, stream,
                       w_qkv, w_out, wqb, wob);
    hipLaunchKernelGGL(qkv_fused_kernel, dim3(1152), dim3(256), 0, stream,
                       x, wqb, qn, kn, vn);
    hipLaunchKernelGGL(attn_mfma_kernel, dim3(2304), dim3(256), 0, stream,
                       qn, kn, vn, Opart, Lpart);
    hipLaunchKernelGGL(out_gemm_kernel, dim3(1152), dim3(256), 0, stream,
                       Opart, Lpart, wob, x, out);
}